// Round 18
// baseline (138.102 us; speedup 1.0000x reference)
//
#include <hip/hip_runtime.h>
#include <hip/hip_bf16.h>
#include <utility>

// out = x @ W.T + 2*b ; M=N=K=4096, fp32 in/out.
// Round 18: R17 champion (108.2us GEMM: triple-A read-ahead pipeline, woven
// ph3 reloads, no setprio, 2 barriers/tile, vmcnt(8), 0 conflicts) + ONE change:
//   6-tile unrolled main loop with COMPILE-TIME buffer-slot indices (LCM of
//   A 3-rotation x B 2-rotation). Removes the runtime pointer rotation: all
//   LDS bases become constants -> per-lane address regs hoisted out of loop,
//   ds_read offset-immediates folded, gll dests literal. Overhead-removal
//   class (the only class that has won: R10 +4%, R17 +5%).

typedef short bf16x8 __attribute__((ext_vector_type(8)));
typedef short s16x4  __attribute__((ext_vector_type(4)));
typedef short s16x8  __attribute__((ext_vector_type(8)));
typedef float f32x4  __attribute__((ext_vector_type(4)));

constexpr int MDIM = 4096, NDIM = 4096, KDIM = 4096;

typedef const __attribute__((address_space(1))) void* gas_t;
typedef __attribute__((address_space(3))) void*       las_t;

template <int N> using ic = std::integral_constant<int, N>;

__device__ __forceinline__ short f2bf(float f) {
    __hip_bfloat16 h = __float2bfloat16(f);   // RNE
    short s; __builtin_memcpy(&s, &h, 2); return s;
}

// ---------------- pass 1: fp32 -> bf16 convert (X and W, one launch) ----------------
__global__ __launch_bounds__(256)
void cvt2_f32_bf16(const float* __restrict__ inA, const float* __restrict__ inB,
                   short* __restrict__ outA, short* __restrict__ outB, int n8each) {
    int idx    = blockIdx.x * blockDim.x + threadIdx.x;
    int stride = gridDim.x * blockDim.x;
    for (int i = idx; i < 2 * n8each; i += stride) {
        const f32x4* in4 = (i < n8each) ? (const f32x4*)inA : (const f32x4*)inB;
        s16x8*      out8 = (i < n8each) ? (s16x8*)outA      : (s16x8*)outB;
        int j = (i < n8each) ? i : i - n8each;
        f32x4 a = in4[2 * j];
        f32x4 b = in4[2 * j + 1];
        s16x8 o = { f2bf(a[0]), f2bf(a[1]), f2bf(a[2]), f2bf(a[3]),
                    f2bf(b[0]), f2bf(b[1]), f2bf(b[2]), f2bf(b[3]) };
        out8[j] = o;
    }
}

// ---------------- pass 2: 256x256 bf16 GEMM (16x16x32), pipelined reads ----------------
constexpr int BM = 256, BN = 256, BK = 64;
constexpr int NT  = KDIM / BK;   // 64 K-tiles
constexpr int ASZ = BM * BK;     // 16384 shorts (32 KiB) per buffer
constexpr int BSZ = BN * BK;
constexpr int AOF[3] = { 0, ASZ, 2 * ASZ };
constexpr int BOF[2] = { 3 * ASZ, 3 * ASZ + BSZ };

// read one A-quadrant (rows rA+Q*32 .. +Q*32+31) into 4 bf16x8
template <int Q>
__device__ __forceinline__ void read_aq(const short* base, int rA, int c0, int c1,
                                        bf16x8 (&dst)[2][2]) {
    #pragma unroll
    for (int m = 0; m < 2; ++m) {
        const short* p = &base[(rA + Q * 32 + m * 16) * BK];
        dst[m][0] = *(const bf16x8*)(p + c0);
        dst[m][1] = *(const bf16x8*)(p + c1);
    }
}

// 16 MFMA for one output quadrant (m, ni, kk-inner) — no setprio (R17 win)
template <int Q>
__device__ __forceinline__ void mfma_quad(const bf16x8 (&af)[2][2], const bf16x8 (&bf)[4][2],
                                          f32x4 (&acc)[8][4]) {
    #pragma unroll
    for (int m = 0; m < 2; ++m)
        #pragma unroll
        for (int ni = 0; ni < 4; ++ni)
            #pragma unroll
            for (int kk = 0; kk < 2; ++kk)
                acc[Q * 2 + m][ni] = __builtin_amdgcn_mfma_f32_16x16x32_bf16(
                    af[m][kk], bf[ni][kk], acc[Q * 2 + m][ni], 0, 0, 0);
}

__global__ __launch_bounds__(512, 2)
void gemm_bf16_256(const short* __restrict__ Xb, const short* __restrict__ Wb,
                   const float* __restrict__ Bv, float* __restrict__ Out)
{
    __shared__ short lds[3 * ASZ + 2 * BSZ];   // 160 KiB: A x3, B x2

    const int tid  = threadIdx.x;
    const int lane = tid & 63;
    const int wid  = tid >> 6;          // 0..7
    const int wr   = wid >> 2;          // 0..1 (M)
    const int wc   = wid & 3;           // 0..3 (N)

    // T1: XCD-chunked block swizzle (nwg=256, divisible by 8 -> bijective)
    const int bid = blockIdx.x;
    const int lin = (bid & 7) * 32 + (bid >> 3);
    const int tm0 = (lin >> 4) * BM;
    const int tn0 = (lin & 15) * BN;

    // ---- staging: linear LDS dest, inverse-swizzled global source ----
    const int srow = lane >> 3;
    const int sgrn = (lane & 7) ^ srow;
    const char* xbase = (const char*)Xb;
    const char* wbase = (const char*)Wb;
    int aOff[2][2], bOff[2][2], dOff[2][2];
    #pragma unroll
    for (int h = 0; h < 2; ++h) {
        #pragma unroll
        for (int j = 0; j < 2; ++j) {
            const int r = h * 128 + (2 * wid + j) * 8;   // segment base row (mult of 8)
            aOff[h][j] = ((tm0 + r + srow) * KDIM + sgrn * 8) * 2;
            bOff[h][j] = ((tn0 + r + srow) * KDIM + sgrn * 8) * 2;
            dOff[h][j] = r * BK;
        }
    }

    // ---- fragment read addressing (swizzled; m89-verified 16x16x32 layout) ----
    const int g   = lane >> 4;          // k-group 0..3 ; D-row group
    const int r16 = lane & 15;          // frag row ; D col
    const int c0  = ((0 + g) ^ (r16 & 7)) * 8;   // kk=0 granule (elements)
    const int c1  = ((4 + g) ^ (r16 & 7)) * 8;   // kk=1
    const int rA  = wr * 128 + r16;
    const int rB  = wc * 64  + r16;

    f32x4 acc[8][4] = {};
    bf16x8 bf[4][2];    // SINGLE B-frag set (reloaded in place inside ph3)
    bf16x8 a0[2][2];    // SINGLE A-q0 set  (reloaded in place at end of ph3)

    auto stageA = [&](int kt, int h, short* dst) {
        const size_t kb = (size_t)kt * (BK * 2);
        __builtin_amdgcn_global_load_lds((gas_t)(xbase + kb + aOff[h][0]),
                                         (las_t)(dst + dOff[h][0]), 16, 0, 0);
        __builtin_amdgcn_global_load_lds((gas_t)(xbase + kb + aOff[h][1]),
                                         (las_t)(dst + dOff[h][1]), 16, 0, 0);
    };
    auto stageB = [&](int kt, int h, short* dst) {
        const size_t kb = (size_t)kt * (BK * 2);
        __builtin_amdgcn_global_load_lds((gas_t)(wbase + kb + bOff[h][0]),
                                         (las_t)(dst + dOff[h][0]), 16, 0, 0);
        __builtin_amdgcn_global_load_lds((gas_t)(wbase + kb + bOff[h][1]),
                                         (las_t)(dst + dOff[h][1]), 16, 0, 0);
    };

    // ---- prologue: stage B(0), A(0), B(1), A(1) ; vmcnt(8) -> (0) landed ----
    {
        #pragma unroll
        for (int h = 0; h < 2; ++h) stageB(0, h, (short*)&lds[BOF[0]]);
        #pragma unroll
        for (int h = 0; h < 2; ++h) stageA(0, h, (short*)&lds[AOF[0]]);
        #pragma unroll
        for (int h = 0; h < 2; ++h) stageB(1, h, (short*)&lds[BOF[1]]);
        #pragma unroll
        for (int h = 0; h < 2; ++h) stageA(1, h, (short*)&lds[AOF[1]]);
        asm volatile("s_waitcnt vmcnt(8)" ::: "memory");   // B(0),A(0) landed; B(1),A(1) in flight
        asm volatile("s_barrier" ::: "memory");
        const short* Bb0 = &lds[BOF[0]];
        #pragma unroll
        for (int ni = 0; ni < 4; ++ni) {
            const short* p = &Bb0[(rB + ni * 16) * BK];
            bf[ni][0] = *(const bf16x8*)(p + c0);
            bf[ni][1] = *(const bf16x8*)(p + c1);
        }
        read_aq<0>(&lds[AOF[0]], rA, c0, c1, a0);
    }

    // ---- tile body: AS = t%3 (A slot), BS = t%2 (B slot), compile-time ----
    auto tile_body = [&](auto asI, auto bsI, int t) {
        constexpr int AS = decltype(asI)::value;
        constexpr int BS = decltype(bsI)::value;
        const short* Ab  = &lds[AOF[AS]];            // A(t)
        const short* AbN = &lds[AOF[(AS + 1) % 3]];  // A(t+1)
        short* dstA      = (short*)&lds[AOF[(AS + 2) % 3]];  // A(t+2) slot
        const short* BbN = &lds[BOF[BS ^ 1]];        // B(t+1)
        short* dstB      = (short*)&lds[BOF[BS]];    // B(t+2) slot (B(t) LDS dead)

        // ---- ph0: read A(t,q1) ; stage A(t+2) both halves ; MFMA q0 (regs)
        bf16x8 aq1[2][2];
        read_aq<1>(Ab, rA, c0, c1, aq1);
        if (t + 2 < NT) { stageA(t + 2, 0, dstA); stageA(t + 2, 1, dstA); }
        mfma_quad<0>(a0, bf, acc);

        // ---- ph1: read A(t,q2) ; stage B(t+2) h0 ; MFMA q1
        bf16x8 aq2[2][2];
        read_aq<2>(Ab, rA, c0, c1, aq2);
        if (t + 2 < NT) stageB(t + 2, 0, dstB);
        mfma_quad<1>(aq1, bf, acc);

        // ---- ph2: read A(t,q3) ; stage B(t+2) h1 ; vmcnt+barrier ; MFMA q2
        bf16x8 aq3[2][2];
        read_aq<3>(Ab, rA, c0, c1, aq3);
        if (t + 2 < NT) stageB(t + 2, 1, dstB);
        // ledger (FIFO): outstanding here = A(t+1)4, B(t+1)4, A(t+2)4, B(t+2)4.
        // vmcnt(8) drains oldest 8 = A(t+1)+B(t+1); (t+2) stays in flight.
        if (t < NT - 2) { asm volatile("s_waitcnt vmcnt(8)" ::: "memory"); }
        else            { asm volatile("s_waitcnt vmcnt(0)" ::: "memory"); }
        asm volatile("s_barrier" ::: "memory");
        mfma_quad<2>(aq2, bf, acc);

        // ---- ph3: MFMA q3 with next-tile B-frag reloads WOVEN IN
        #pragma unroll
        for (int ni = 0; ni < 4; ++ni) {
            #pragma unroll
            for (int kk = 0; kk < 2; ++kk) {
                const int cc = kk ? c1 : c0;
                acc[6][ni] = __builtin_amdgcn_mfma_f32_16x16x32_bf16(
                                 aq3[0][kk], bf[ni][kk], acc[6][ni], 0, 0, 0);
                acc[7][ni] = __builtin_amdgcn_mfma_f32_16x16x32_bf16(
                                 aq3[1][kk], bf[ni][kk], acc[7][ni], 0, 0, 0);
                if (t + 1 < NT)
                    bf[ni][kk] = *(const bf16x8*)(&BbN[(rB + ni * 16) * BK] + cc);
            }
        }
        if (t + 1 < NT) read_aq<0>(AbN, rA, c0, c1, a0);
        asm volatile("s_barrier" ::: "memory");   // tile-t reads done before next stages land
    };

    // ---- main loop: 6-tile unroll (LCM of 3-slot A x 2-slot B), static slots ----
    int t = 0;
    for (; t + 6 <= NT; t += 6) {
        tile_body(ic<0>{}, ic<0>{}, t);
        tile_body(ic<1>{}, ic<1>{}, t + 1);
        tile_body(ic<2>{}, ic<0>{}, t + 2);
        tile_body(ic<0>{}, ic<1>{}, t + 3);
        tile_body(ic<1>{}, ic<0>{}, t + 4);
        tile_body(ic<2>{}, ic<1>{}, t + 5);
    }
    // NT=64: 4 peeled tiles (t=60..63), parities continue the 6-cycle
    tile_body(ic<0>{}, ic<0>{}, 60);
    tile_body(ic<1>{}, ic<1>{}, 61);
    tile_body(ic<2>{}, ic<0>{}, 62);
    tile_body(ic<0>{}, ic<1>{}, 63);

    // ---- epilogue: + 2*bias, fp32 store ----
    float bb[4];
    #pragma unroll
    for (int ni = 0; ni < 4; ++ni)
        bb[ni] = 2.0f * Bv[tn0 + wc * 64 + ni * 16 + r16];

    #pragma unroll
    for (int mi = 0; mi < 8; ++mi) {
        #pragma unroll
        for (int r = 0; r < 4; ++r) {
            const int row = tm0 + wr * 128 + mi * 16 + g * 4 + r;
            float* orow = Out + (size_t)row * NDIM + tn0 + wc * 64 + r16;
            #pragma unroll
            for (int ni = 0; ni < 4; ++ni)
                orow[ni * 16] = acc[mi][ni][r] + bb[ni];
        }
    }
}

// ---------------- fallback: fp32 reg-staged (if ws too small) ----------------
constexpr int FBM = 128, FBN = 128, FBK = 32, LDT = FBK + 8;
__global__ __launch_bounds__(256)
void gemm_xwt_bias2(const float* __restrict__ X, const float* __restrict__ W,
                    const float* __restrict__ Bv, float* __restrict__ Out)
{
    __shared__ short As[FBM * LDT];
    __shared__ short Bs[FBN * LDT];
    const int tid  = threadIdx.x;
    const int lane = tid & 63;
    const int wid  = tid >> 6;
    const int wr   = wid >> 1;
    const int wc   = wid & 1;
    const int tm0  = blockIdx.y * FBM;
    const int tn0  = blockIdx.x * FBN;
    const int srow = tid >> 3;
    const int scol = (tid & 7) * 4;
    const int g    = lane >> 4;
    const int r16  = lane & 15;
    f32x4 acc[4][4] = {};
    const float* xg = X + (size_t)(tm0 + srow) * KDIM + scol;
    const float* wg = W + (size_t)(tn0 + srow) * KDIM + scol;
    for (int k0 = 0; k0 < KDIM; k0 += FBK) {
        #pragma unroll
        for (int i = 0; i < 4; ++i) {
            const int row = srow + 32 * i;
            f32x4 av = *(const f32x4*)(xg + (size_t)(32 * i) * KDIM + k0);
            f32x4 bv = *(const f32x4*)(wg + (size_t)(32 * i) * KDIM + k0);
            s16x4 pa = { f2bf(av[0]), f2bf(av[1]), f2bf(av[2]), f2bf(av[3]) };
            s16x4 pb = { f2bf(bv[0]), f2bf(bv[1]), f2bf(bv[2]), f2bf(bv[3]) };
            *(s16x4*)&As[row * LDT + scol] = pa;
            *(s16x4*)&Bs[row * LDT + scol] = pb;
        }
        __syncthreads();
        bf16x8 af[4], bfr[4];
        #pragma unroll
        for (int mi = 0; mi < 4; ++mi)
            af[mi] = *(const bf16x8*)&As[(wr * 64 + mi * 16 + r16) * LDT + g * 8];
        #pragma unroll
        for (int ni = 0; ni < 4; ++ni)
            bfr[ni] = *(const bf16x8*)&Bs[(wc * 64 + ni * 16 + r16) * LDT + g * 8];
        #pragma unroll
        for (int mi = 0; mi < 4; ++mi)
            #pragma unroll
            for (int ni = 0; ni < 4; ++ni)
                acc[mi][ni] = __builtin_amdgcn_mfma_f32_16x16x32_bf16(
                                  af[mi], bfr[ni], acc[mi][ni], 0, 0, 0);
        __syncthreads();
    }
    float bb[4];
    #pragma unroll
    for (int ni = 0; ni < 4; ++ni)
        bb[ni] = 2.0f * Bv[tn0 + wc * 64 + ni * 16 + r16];
    #pragma unroll
    for (int mi = 0; mi < 4; ++mi)
        #pragma unroll
        for (int r = 0; r < 4; ++r) {
            const int row = tm0 + wr * 64 + mi * 16 + g * 4 + r;
            float* orow = Out + (size_t)row * NDIM + tn0 + wc * 64 + r16;
            #pragma unroll
            for (int ni = 0; ni < 4; ++ni)
                orow[ni * 16] = acc[mi][ni][r] + bb[ni];
        }
}

extern "C" void kernel_launch(void* const* d_in, const int* in_sizes, int n_in,
                              void* d_out, int out_size, void* d_ws, size_t ws_size,
                              hipStream_t stream) {
    const float* X  = (const float*)d_in[0];
    const float* W  = (const float*)d_in[1];
    const float* Bv = (const float*)d_in[2];
    float* Out = (float*)d_out;

    const size_t nElem = (size_t)MDIM * KDIM;
    const size_t need  = 2 * nElem * sizeof(short);   // 67.1 MB

    if (ws_size >= need) {
        short* Xb = (short*)d_ws;
        short* Wb = Xb + nElem;
        const int n8 = (int)(nElem / 8);
        cvt2_f32_bf16<<<4096, 256, 0, stream>>>(X, W, Xb, Wb, n8);
        gemm_bf16_256<<<dim3(256), 512, 0, stream>>>(Xb, Wb, Bv, Out);
    } else {
        dim3 grid(NDIM / FBN, MDIM / FBM);
        gemm_xwt_bias2<<<grid, 256, 0, stream>>>(X, W, Bv, Out);
    }
}

// Round 19
// 133.253 us; speedup vs baseline: 1.0364x; 1.0364x over previous
//
#include <hip/hip_runtime.h>
#include <hip/hip_bf16.h>

// out = x @ W.T + 2*b ; M=N=K=4096, fp32 in/out.
// Round 19 (FINAL): restore R17 champion byte-for-byte (108.2us GEMM / 133.4us
// total). Structure: fp32->bf16 pre-convert into d_ws, then 256x256 bf16 GEMM
// (16x16x32 MFMA), read-one-phase-ahead pipeline, TRIPLE-buffered A +
// double-buffered B (160KB LDS), 2 barriers/tile, counted vmcnt(8) drain,
// woven ph3 next-tile fragment reloads, NO setprio (R17: +5%), T1 XCD swizzle,
// T2 granule-XOR swizzle (0 bank conflicts).
// Closed axes: geometry (R16), MFMA shape (R14), schedule order (R9/11/13),
// static addressing (R18: code bloat loses), fp8 (error budget fails).

typedef short bf16x8 __attribute__((ext_vector_type(8)));
typedef short s16x4  __attribute__((ext_vector_type(4)));
typedef short s16x8  __attribute__((ext_vector_type(8)));
typedef float f32x4  __attribute__((ext_vector_type(4)));

constexpr int MDIM = 4096, NDIM = 4096, KDIM = 4096;

typedef const __attribute__((address_space(1))) void* gas_t;
typedef __attribute__((address_space(3))) void*       las_t;

__device__ __forceinline__ short f2bf(float f) {
    __hip_bfloat16 h = __float2bfloat16(f);   // RNE
    short s; __builtin_memcpy(&s, &h, 2); return s;
}

// ---------------- pass 1: fp32 -> bf16 convert (X and W, one launch) ----------------
__global__ __launch_bounds__(256)
void cvt2_f32_bf16(const float* __restrict__ inA, const float* __restrict__ inB,
                   short* __restrict__ outA, short* __restrict__ outB, int n8each) {
    int idx    = blockIdx.x * blockDim.x + threadIdx.x;
    int stride = gridDim.x * blockDim.x;
    for (int i = idx; i < 2 * n8each; i += stride) {
        const f32x4* in4 = (i < n8each) ? (const f32x4*)inA : (const f32x4*)inB;
        s16x8*      out8 = (i < n8each) ? (s16x8*)outA      : (s16x8*)outB;
        int j = (i < n8each) ? i : i - n8each;
        f32x4 a = in4[2 * j];
        f32x4 b = in4[2 * j + 1];
        s16x8 o = { f2bf(a[0]), f2bf(a[1]), f2bf(a[2]), f2bf(a[3]),
                    f2bf(b[0]), f2bf(b[1]), f2bf(b[2]), f2bf(b[3]) };
        out8[j] = o;
    }
}

// ---------------- pass 2: 256x256 bf16 GEMM (16x16x32), pipelined reads ----------------
constexpr int BM = 256, BN = 256, BK = 64;
constexpr int NT  = KDIM / BK;   // 64 K-tiles
constexpr int ASZ = BM * BK;     // 16384 shorts (32 KiB) per buffer
constexpr int BSZ = BN * BK;

// read one A-quadrant (rows rA+Q*32 .. +Q*32+31) into 4 bf16x8
template <int Q>
__device__ __forceinline__ void read_aq(const short* base, int rA, int c0, int c1,
                                        bf16x8 (&dst)[2][2]) {
    #pragma unroll
    for (int m = 0; m < 2; ++m) {
        const short* p = &base[(rA + Q * 32 + m * 16) * BK];
        dst[m][0] = *(const bf16x8*)(p + c0);
        dst[m][1] = *(const bf16x8*)(p + c1);
    }
}

// 16 MFMA for one output quadrant (m, ni, kk-inner) — no setprio (R17 win)
template <int Q>
__device__ __forceinline__ void mfma_quad(const bf16x8 (&af)[2][2], const bf16x8 (&bf)[4][2],
                                          f32x4 (&acc)[8][4]) {
    #pragma unroll
    for (int m = 0; m < 2; ++m)
        #pragma unroll
        for (int ni = 0; ni < 4; ++ni)
            #pragma unroll
            for (int kk = 0; kk < 2; ++kk)
                acc[Q * 2 + m][ni] = __builtin_amdgcn_mfma_f32_16x16x32_bf16(
                    af[m][kk], bf[ni][kk], acc[Q * 2 + m][ni], 0, 0, 0);
}

__global__ __launch_bounds__(512, 2)
void gemm_bf16_256(const short* __restrict__ Xb, const short* __restrict__ Wb,
                   const float* __restrict__ Bv, float* __restrict__ Out)
{
    __shared__ short lds[3 * ASZ + 2 * BSZ];   // 160 KiB: A x3, B x2

    const int tid  = threadIdx.x;
    const int lane = tid & 63;
    const int wid  = tid >> 6;          // 0..7
    const int wr   = wid >> 2;          // 0..1 (M)
    const int wc   = wid & 3;           // 0..3 (N)

    // T1: XCD-chunked block swizzle (nwg=256, divisible by 8 -> bijective)
    const int bid = blockIdx.x;
    const int lin = (bid & 7) * 32 + (bid >> 3);
    const int tm0 = (lin >> 4) * BM;
    const int tn0 = (lin & 15) * BN;

    // ---- staging: linear LDS dest, inverse-swizzled global source ----
    const int srow = lane >> 3;
    const int sgrn = (lane & 7) ^ srow;
    const char* xbase = (const char*)Xb;
    const char* wbase = (const char*)Wb;
    int aOff[2][2], bOff[2][2], dOff[2][2];
    #pragma unroll
    for (int h = 0; h < 2; ++h) {
        #pragma unroll
        for (int j = 0; j < 2; ++j) {
            const int r = h * 128 + (2 * wid + j) * 8;   // segment base row (mult of 8)
            aOff[h][j] = ((tm0 + r + srow) * KDIM + sgrn * 8) * 2;
            bOff[h][j] = ((tn0 + r + srow) * KDIM + sgrn * 8) * 2;
            dOff[h][j] = r * BK;
        }
    }

    // ---- fragment read addressing (swizzled; m89-verified 16x16x32 layout) ----
    const int g   = lane >> 4;          // k-group 0..3 ; D-row group
    const int r16 = lane & 15;          // frag row ; D col
    const int c0  = ((0 + g) ^ (r16 & 7)) * 8;   // kk=0 granule (elements)
    const int c1  = ((4 + g) ^ (r16 & 7)) * 8;   // kk=1
    const int rA  = wr * 128 + r16;
    const int rB  = wc * 64  + r16;

    f32x4 acc[8][4] = {};
    bf16x8 bf[4][2];    // SINGLE B-frag set (reloaded in place inside ph3)
    bf16x8 a0[2][2];    // SINGLE A-q0 set  (reloaded in place at end of ph3)

    auto stageA = [&](int kt, int h, short* dst) {
        const size_t kb = (size_t)kt * (BK * 2);
        __builtin_amdgcn_global_load_lds((gas_t)(xbase + kb + aOff[h][0]),
                                         (las_t)(dst + dOff[h][0]), 16, 0, 0);
        __builtin_amdgcn_global_load_lds((gas_t)(xbase + kb + aOff[h][1]),
                                         (las_t)(dst + dOff[h][1]), 16, 0, 0);
    };
    auto stageB = [&](int kt, int h, short* dst) {
        const size_t kb = (size_t)kt * (BK * 2);
        __builtin_amdgcn_global_load_lds((gas_t)(wbase + kb + bOff[h][0]),
                                         (las_t)(dst + dOff[h][0]), 16, 0, 0);
        __builtin_amdgcn_global_load_lds((gas_t)(wbase + kb + bOff[h][1]),
                                         (las_t)(dst + dOff[h][1]), 16, 0, 0);
    };

    // buffer pointers (wave-uniform, rotated per tile)
    short* aSlot0 = (short*)&lds[0];
    short* aSlot1 = (short*)&lds[ASZ];
    short* aSlot2 = (short*)&lds[2 * ASZ];
    short* bSlot0 = (short*)&lds[3 * ASZ];
    short* bSlot1 = (short*)&lds[3 * ASZ + BSZ];

    // ---- prologue: stage B(0), A(0), B(1), A(1) ; vmcnt(8) -> (0) landed ----
    {
        #pragma unroll
        for (int h = 0; h < 2; ++h) stageB(0, h, bSlot0);
        #pragma unroll
        for (int h = 0; h < 2; ++h) stageA(0, h, aSlot0);
        #pragma unroll
        for (int h = 0; h < 2; ++h) stageB(1, h, bSlot1);
        #pragma unroll
        for (int h = 0; h < 2; ++h) stageA(1, h, aSlot1);
        asm volatile("s_waitcnt vmcnt(8)" ::: "memory");   // B(0),A(0) landed; B(1),A(1) in flight
        asm volatile("s_barrier" ::: "memory");
        #pragma unroll
        for (int ni = 0; ni < 4; ++ni) {
            const short* p = &bSlot0[(rB + ni * 16) * BK];
            bf[ni][0] = *(const bf16x8*)(p + c0);
            bf[ni][1] = *(const bf16x8*)(p + c1);
        }
        read_aq<0>(aSlot0, rA, c0, c1, a0);
    }

    // ---- main loop: per tile t, buffers: A reads aCur, next-tile reads aNxt,
    //      A(t+2) staged into aStg; B reads (woven) bNxt, B(t+2) staged into bCur.
    short* aCur = aSlot0; short* aNxt = aSlot1; short* aStg = aSlot2;
    short* bCur = bSlot0; short* bNxt = bSlot1;

    for (int t = 0; t < NT; ++t) {
        // ---- ph0: read A(t,q1) ; stage A(t+2) both halves ; MFMA q0 (regs)
        bf16x8 aq1[2][2];
        read_aq<1>(aCur, rA, c0, c1, aq1);
        if (t + 2 < NT) { stageA(t + 2, 0, aStg); stageA(t + 2, 1, aStg); }
        mfma_quad<0>(a0, bf, acc);

        // ---- ph1: read A(t,q2) ; stage B(t+2) h0 ; MFMA q1
        bf16x8 aq2[2][2];
        read_aq<2>(aCur, rA, c0, c1, aq2);
        if (t + 2 < NT) stageB(t + 2, 0, bCur);
        mfma_quad<1>(aq1, bf, acc);

        // ---- ph2: read A(t,q3) ; stage B(t+2) h1 ; vmcnt+barrier ; MFMA q2
        bf16x8 aq3[2][2];
        read_aq<3>(aCur, rA, c0, c1, aq3);
        if (t + 2 < NT) stageB(t + 2, 1, bCur);
        // ledger (FIFO): outstanding here = A(t+1)4, B(t+1)4, A(t+2)4, B(t+2)4.
        // vmcnt(8) drains oldest 8 = A(t+1)+B(t+1); (t+2) stays in flight.
        // A-slack 6 phases (staged t-1.ph0, drained t.ph2-end).
        if (t < NT - 2) { asm volatile("s_waitcnt vmcnt(8)" ::: "memory"); }
        else            { asm volatile("s_waitcnt vmcnt(0)" ::: "memory"); }
        asm volatile("s_barrier" ::: "memory");
        mfma_quad<2>(aq2, bf, acc);

        // ---- ph3: MFMA q3 with next-tile B-frag reloads WOVEN IN
        #pragma unroll
        for (int ni = 0; ni < 4; ++ni) {
            #pragma unroll
            for (int kk = 0; kk < 2; ++kk) {
                const int cc = kk ? c1 : c0;
                acc[6][ni] = __builtin_amdgcn_mfma_f32_16x16x32_bf16(
                                 aq3[0][kk], bf[ni][kk], acc[6][ni], 0, 0, 0);
                acc[7][ni] = __builtin_amdgcn_mfma_f32_16x16x32_bf16(
                                 aq3[1][kk], bf[ni][kk], acc[7][ni], 0, 0, 0);
                if (t + 1 < NT)
                    bf[ni][kk] = *(const bf16x8*)(&bNxt[(rB + ni * 16) * BK] + cc);
            }
        }
        if (t + 1 < NT) read_aq<0>(aNxt, rA, c0, c1, a0);
        asm volatile("s_barrier" ::: "memory");   // tile-t reads done before next stages land

        // rotate buffers
        short* tmp = aCur; aCur = aNxt; aNxt = aStg; aStg = tmp;
        tmp = bCur; bCur = bNxt; bNxt = tmp;
    }

    // ---- epilogue: + 2*bias, fp32 store ----
    float bb[4];
    #pragma unroll
    for (int ni = 0; ni < 4; ++ni)
        bb[ni] = 2.0f * Bv[tn0 + wc * 64 + ni * 16 + r16];

    #pragma unroll
    for (int mi = 0; mi < 8; ++mi) {
        #pragma unroll
        for (int r = 0; r < 4; ++r) {
            const int row = tm0 + wr * 128 + mi * 16 + g * 4 + r;
            float* orow = Out + (size_t)row * NDIM + tn0 + wc * 64 + r16;
            #pragma unroll
            for (int ni = 0; ni < 4; ++ni)
                orow[ni * 16] = acc[mi][ni][r] + bb[ni];
        }
    }
}

// ---------------- fallback: fp32 reg-staged (if ws too small) ----------------
constexpr int FBM = 128, FBN = 128, FBK = 32, LDT = FBK + 8;
__global__ __launch_bounds__(256)
void gemm_xwt_bias2(const float* __restrict__ X, const float* __restrict__ W,
                    const float* __restrict__ Bv, float* __restrict__ Out)
{
    __shared__ short As[FBM * LDT];
    __shared__ short Bs[FBN * LDT];
    const int tid  = threadIdx.x;
    const int lane = tid & 63;
    const int wid  = tid >> 6;
    const int wr   = wid >> 1;
    const int wc   = wid & 1;
    const int tm0  = blockIdx.y * FBM;
    const int tn0  = blockIdx.x * FBN;
    const int srow = tid >> 3;
    const int scol = (tid & 7) * 4;
    const int g    = lane >> 4;
    const int r16  = lane & 15;
    f32x4 acc[4][4] = {};
    const float* xg = X + (size_t)(tm0 + srow) * KDIM + scol;
    const float* wg = W + (size_t)(tn0 + srow) * KDIM + scol;
    for (int k0 = 0; k0 < KDIM; k0 += FBK) {
        #pragma unroll
        for (int i = 0; i < 4; ++i) {
            const int row = srow + 32 * i;
            f32x4 av = *(const f32x4*)(xg + (size_t)(32 * i) * KDIM + k0);
            f32x4 bv = *(const f32x4*)(wg + (size_t)(32 * i) * KDIM + k0);
            s16x4 pa = { f2bf(av[0]), f2bf(av[1]), f2bf(av[2]), f2bf(av[3]) };
            s16x4 pb = { f2bf(bv[0]), f2bf(bv[1]), f2bf(bv[2]), f2bf(bv[3]) };
            *(s16x4*)&As[row * LDT + scol] = pa;
            *(s16x4*)&Bs[row * LDT + scol] = pb;
        }
        __syncthreads();
        bf16x8 af[4], bfr[4];
        #pragma unroll
        for (int mi = 0; mi < 4; ++mi)
            af[mi] = *(const bf16x8*)&As[(wr * 64 + mi * 16 + r16) * LDT + g * 8];
        #pragma unroll
        for (int ni = 0; ni < 4; ++ni)
            bfr[ni] = *(const bf16x8*)&Bs[(wc * 64 + ni * 16 + r16) * LDT + g * 8];
        #pragma unroll
        for (int mi = 0; mi < 4; ++mi)
            #pragma unroll
            for (int ni = 0; ni < 4; ++ni)
                acc[mi][ni] = __builtin_amdgcn_mfma_f32_16x16x32_bf16(
                                  af[mi], bfr[ni], acc[mi][ni], 0, 0, 0);
        __syncthreads();
    }
    float bb[4];
    #pragma unroll
    for (int ni = 0; ni < 4; ++ni)
        bb[ni] = 2.0f * Bv[tn0 + wc * 64 + ni * 16 + r16];
    #pragma unroll
    for (int mi = 0; mi < 4; ++mi)
        #pragma unroll
        for (int r = 0; r < 4; ++r) {
            const int row = tm0 + wr * 64 + mi * 16 + g * 4 + r;
            float* orow = Out + (size_t)row * NDIM + tn0 + wc * 64 + r16;
            #pragma unroll
            for (int ni = 0; ni < 4; ++ni)
                orow[ni * 16] = acc[mi][ni][r] + bb[ni];
        }
}

extern "C" void kernel_launch(void* const* d_in, const int* in_sizes, int n_in,
                              void* d_out, int out_size, void* d_ws, size_t ws_size,
                              hipStream_t stream) {
    const float* X  = (const float*)d_in[0];
    const float* W  = (const float*)d_in[1];
    const float* Bv = (const float*)d_in[2];
    float* Out = (float*)d_out;

    const size_t nElem = (size_t)MDIM * KDIM;
    const size_t need  = 2 * nElem * sizeof(short);   // 67.1 MB

    if (ws_size >= need) {
        short* Xb = (short*)d_ws;
        short* Wb = Xb + nElem;
        const int n8 = (int)(nElem / 8);
        cvt2_f32_bf16<<<4096, 256, 0, stream>>>(X, W, Xb, Wb, n8);
        gemm_bf16_256<<<dim3(256), 512, 0, stream>>>(Xb, Wb, Bv, Out);
    } else {
        dim3 grid(NDIM / FBN, MDIM / FBM);
        gemm_xwt_bias2<<<grid, 256, 0, stream>>>(X, W, Bv, Out);
    }
}